// Round 2
// baseline (625.623 us; speedup 1.0000x reference)
//
#include <hip/hip_runtime.h>

// Y[n,m,t] = mean_d (X1[n,t,d]-X2[m,t,d])^2
//          = (||x1||^2 - 2<x1,x2> + ||x2||^2)/D, cross via f16 MFMA.
// N=M=1024, T=64, D=128. Output [N,M,T] fp32, t innermost.
//
// Round-2 restructure (theory: latency-bound, 1 block/CU lockstep barriers):
//  * 512-thr blocks (8 waves), tile 64(n) x 32(m) x 16(t). acc[16] f32x4 =
//    64 VGPR; <=128 VGPR cap -> 4 waves/SIMD -> TWO independent blocks/CU.
//  * double-buffered As/Bs -> ONE __syncthreads per t (16 vs 32 barriers).
//    Safety: write buf[t&1] -> barrier(t) -> read buf[t&1]; reuse of a
//    buffer at t+2 is fenced by barrier(t+1).
//  * prefetch t+1 issued right after the barrier, consumed after the MFMA
//    phase of t (same distance as round-1, but now a co-resident block
//    covers the remaining stall).
//  * verified round-1 layouts preserved: fragment indexing, C/D mapping
//    (col=lane&15 -> m, row=(lane>>4)*4+reg -> n), one lane owns a full
//    64B output line (4x f32x4 back-to-back).

#define NN 1024
#define MM 1024
#define TT 64
#define DD 128

typedef _Float16 f16x8 __attribute__((ext_vector_type(8)));
typedef float f32x4 __attribute__((ext_vector_type(4)));

#define LDA 132   // f16 elems per LDS row (128 + 4 pad -> bank rotation)
#define LDN 17    // norm row stride in floats (conflict-free epilogue reads)

__global__ __launch_bounds__(512, 4) void sim_kernel(
    const float* __restrict__ X1, const float* __restrict__ X2,
    float* __restrict__ Y)
{
    __shared__ _Float16 As[2][64 * LDA];   // 2 x 16.9 KB
    __shared__ _Float16 Bs[2][32 * LDA];   // 2 x 8.4 KB
    __shared__ float an[64 * LDN];
    __shared__ float bn[32 * LDN];
    // total ~55.9 KB -> 2 blocks/CU fit in 160 KB

    // swizzled block id: 2048 blocks = 512 (n,m)-tiles x 4 t-groups.
    // low 3 bits preserved -> same-XCD neighbors share A/B tiles.
    const int b   = blockIdx.x;
    const int clo = b & 7;
    const int tg  = (b >> 3) & 3;
    const int chi = b >> 5;
    const int c   = (chi << 3) | clo;     // (n,m) tile id 0..511
    const int n0  = (c >> 5) << 6;        // 16 n-tiles of 64
    const int m0  = (c & 31) << 5;        // 32 m-tiles of 32
    const int t0  = tg << 4;

    const int tid  = threadIdx.x;
    const int lane = tid & 63;
    const int wave = tid >> 6;                 // 0..7
    const int q = lane >> 4, r = lane & 15;
    const int wn = wave >> 1, wm = wave & 1;   // 4x2 wave grid over 64x32

    // A staging: 8 thr/row x 64 rows, 16 consecutive floats (64B) each.
    const int arow = tid >> 3;
    const int acol = (tid & 7) << 4;
    // B staging: 16 thr/row x 32 rows, 8 consecutive floats (32B) each.
    const int brow = tid >> 4;
    const int bcol = (tid & 15) << 3;

    const float* pA = X1 + ((size_t)(n0 + arow) * TT + t0) * DD + acol;
    const float* pB = X2 + ((size_t)(m0 + brow) * TT + t0) * DD + bcol;

    f32x4 acc[16];
    #pragma unroll
    for (int i = 0; i < 16; ++i) acc[i] = (f32x4){0.f, 0.f, 0.f, 0.f};

    // prologue: loads for tl = 0
    f32x4 uA[4];
    f32x4 uB[2];
    uA[0] = ((const f32x4*)pA)[0]; uA[1] = ((const f32x4*)pA)[1];
    uA[2] = ((const f32x4*)pA)[2]; uA[3] = ((const f32x4*)pA)[3];
    uB[0] = ((const f32x4*)pB)[0]; uB[1] = ((const f32x4*)pB)[1];

    #pragma unroll
    for (int tl = 0; tl < 16; ++tl) {
        _Float16* __restrict__ Abuf = As[tl & 1];
        _Float16* __restrict__ Bbuf = Bs[tl & 1];

        // fp32 sumsq + convert to f16 (in registers)
        float sA = 0.f;
        #pragma unroll
        for (int j = 0; j < 4; ++j)
            sA += uA[j][0]*uA[j][0] + uA[j][1]*uA[j][1]
                + uA[j][2]*uA[j][2] + uA[j][3]*uA[j][3];
        f16x8 hA0, hA1;
        #pragma unroll
        for (int e = 0; e < 4; ++e) { hA0[e] = (_Float16)uA[0][e]; hA0[e+4] = (_Float16)uA[1][e]; }
        #pragma unroll
        for (int e = 0; e < 4; ++e) { hA1[e] = (_Float16)uA[2][e]; hA1[e+4] = (_Float16)uA[3][e]; }
        sA += __shfl_xor(sA, 1); sA += __shfl_xor(sA, 2); sA += __shfl_xor(sA, 4);

        float sB = uB[0][0]*uB[0][0] + uB[0][1]*uB[0][1]
                 + uB[0][2]*uB[0][2] + uB[0][3]*uB[0][3]
                 + uB[1][0]*uB[1][0] + uB[1][1]*uB[1][1]
                 + uB[1][2]*uB[1][2] + uB[1][3]*uB[1][3];
        f16x8 hB;
        #pragma unroll
        for (int e = 0; e < 4; ++e) { hB[e] = (_Float16)uB[0][e]; hB[e+4] = (_Float16)uB[1][e]; }
        sB += __shfl_xor(sB, 1); sB += __shfl_xor(sB, 2);
        sB += __shfl_xor(sB, 4); sB += __shfl_xor(sB, 8);

        *(f16x8*)&Abuf[arow * LDA + acol]     = hA0;
        *(f16x8*)&Abuf[arow * LDA + acol + 8] = hA1;
        *(f16x8*)&Bbuf[brow * LDA + bcol]     = hB;
        if ((tid & 7)  == 0) an[arow * LDN + tl] = sA;
        if ((tid & 15) == 0) bn[brow * LDN + tl] = sB;

        __syncthreads();   // staging(t) visible; fences buf reuse from t-2

        // prefetch next t (in flight across the MFMA phase)
        if (tl < 15) {
            const float* nA = pA + (size_t)(tl + 1) * DD;
            const float* nB = pB + (size_t)(tl + 1) * DD;
            uA[0] = ((const f32x4*)nA)[0]; uA[1] = ((const f32x4*)nA)[1];
            uA[2] = ((const f32x4*)nA)[2]; uA[3] = ((const f32x4*)nA)[3];
            uB[0] = ((const f32x4*)nB)[0]; uB[1] = ((const f32x4*)nB)[1];
        }

        // fragments + MFMA: wave's 16x16 tile, K = 128 in 4 chunks
        #pragma unroll
        for (int kc = 0; kc < 4; ++kc) {
            f16x8 af = *(const f16x8*)&Abuf[(wn*16 + r) * LDA + kc*32 + q*8];
            f16x8 bf = *(const f16x8*)&Bbuf[(wm*16 + r) * LDA + kc*32 + q*8];
            acc[tl] = __builtin_amdgcn_mfma_f32_16x16x32_f16(af, bf, acc[tl], 0, 0, 0);
        }
    }

    // epilogue: C/D layout (16x16): col(m)=lane&15, row(n)=(lane>>4)*4+reg
    float bnv[16];
    {
        const float* pb = &bn[(wm*16 + r) * LDN];
        #pragma unroll
        for (int e = 0; e < 16; ++e) bnv[e] = pb[e];
    }
    const float inv = 1.0f / 128.0f;
    #pragma unroll
    for (int rr = 0; rr < 4; ++rr) {
        const float* pa = &an[(wn*16 + q*4 + rr) * LDN];
        float anv[16];
        #pragma unroll
        for (int e = 0; e < 16; ++e) anv[e] = pa[e];
        const size_t n = (size_t)(n0 + wn*16 + q*4 + rr);
        const size_t m = (size_t)(m0 + wm*16 + r);
        float* yb = Y + (n * MM + m) * TT + t0;
        #pragma unroll
        for (int tq = 0; tq < 4; ++tq) {
            f32x4 o;
            #pragma unroll
            for (int e = 0; e < 4; ++e) {
                const int tl = tq*4 + e;
                o[e] = (anv[tl] + bnv[tl] - 2.0f * acc[tl][rr]) * inv;
            }
            ((f32x4*)yb)[tq] = o;   // 4 back-to-back 16B -> one full 64B line
        }
    }
}

extern "C" void kernel_launch(void* const* d_in, const int* in_sizes, int n_in,
                              void* d_out, int out_size, void* d_ws, size_t ws_size,
                              hipStream_t stream) {
    const float* X1 = (const float*)d_in[0];
    const float* X2 = (const float*)d_in[1];
    float* Y = (float*)d_out;
    sim_kernel<<<dim3(2048), dim3(512), 0, stream>>>(X1, X2, Y);
}

// Round 3
// 456.014 us; speedup vs baseline: 1.3719x; 1.3719x over previous
//
#include <hip/hip_runtime.h>
#include <stdint.h>

// Y[n,m,t] = mean_d (X1[n,t,d]-X2[m,t,d])^2
//          = (||x1||^2 - 2<x1,x2> + ||x2||^2)/D, cross via f16 MFMA.
// N=M=1024, T=64, D=128. Output [N,M,T] fp32, t innermost.
//
// Round-3: theory = bound by 1.5 GB of redundant fp32 input reads through
// the L3 path (~4 TB/s effective), with VALU convert + vmcnt(0) barrier
// drains serializing the loop (MfmaUtil 1.8%, VALUBusy 8%, HBM 19%).
//  * prep_kernel: X -> f16 in ws, t-major Xh[t][n][d'], with the LDS
//    bank-swizzle BAKED into d' (d_u32' = d_u32 ^ ((n&7)<<2)); also
//    precomputes norms n1[n][t], n2[m][t]. Read bytes halve (768 MB),
//    main loop loses its entire VALU phase.
//  * sim_kernel: per t-step, A(64x128)/B(32x128) f16 slabs are CONTIGUOUS
//    16/8 KB chunks -> staged with global_load_lds width=16, double
//    buffered, raw s_barrier + counted vmcnt(3) (loads stay in flight
//    across barriers). Fragment ds_read_b128 is bank-conflict-free via
//    the baked XOR swizzle.
//  * XCD-chunked bijective block swizzle (2048%8==0) for A-slab L2 reuse.
//  * epilogue unchanged (verified): C/D col=lane&15 -> m, row=(q*4+reg)
//    -> n; each lane writes a full 64B line of Y as 4x f32x4.

#define NN 1024
#define MM 1024
#define TT 64
#define DD 128

typedef _Float16 f16x8 __attribute__((ext_vector_type(8)));
typedef float f32x4 __attribute__((ext_vector_type(4)));
typedef float f32x2 __attribute__((ext_vector_type(2)));

// ws layout (bytes)
#define X1H_OFF 0u
#define X2H_OFF (16u << 20)
#define N1_OFF  (32u << 20)
#define N2_OFF  ((32u << 20) + (256u << 10))
#define WS_NEED ((size_t)(32u << 20) + (512u << 10))

// ---------------- pre-pass: f32 -> swizzled t-major f16 + norms ----------
__global__ __launch_bounds__(256) void prep_kernel(
    const float* __restrict__ X1, const float* __restrict__ X2,
    uint32_t* __restrict__ ws)
{
    const int lane = threadIdx.x & 63;
    const int wv   = threadIdx.x >> 6;
    const int gid  = blockIdx.x * 4 + wv;      // 0..131071 = src*65536+n*64+t
    const int src  = gid >> 16;
    const int rem  = gid & 65535;
    const int n    = rem >> 6;
    const int t    = rem & 63;

    const float* X  = src ? X2 : X1;
    uint32_t* Xh    = ws + ((src ? X2H_OFF : X1H_OFF) >> 2);
    float*    nrm   = (float*)ws + ((src ? N2_OFF : N1_OFF) >> 2);

    f32x2 v = *(const f32x2*)&X[((size_t)n * TT + t) * DD + lane * 2];
    float s = v[0]*v[0] + v[1]*v[1];
    union { uint32_t u; _Float16 h[2]; } pk;
    pk.h[0] = (_Float16)v[0]; pk.h[1] = (_Float16)v[1];
    // row (t,n): 64 u32; in-row u32 slot = lane ^ ((n&7)<<2)  (bank swizzle)
    Xh[(size_t)(t * NN + n) * 64 + (lane ^ ((n & 7) << 2))] = pk.u;

    s += __shfl_xor(s, 1);  s += __shfl_xor(s, 2);  s += __shfl_xor(s, 4);
    s += __shfl_xor(s, 8);  s += __shfl_xor(s, 16); s += __shfl_xor(s, 32);
    if (lane == 0) nrm[n * TT + t] = s;
}

// ---------------- main kernel: DMA-staged f16 MFMA ----------------------
#define STAGE(ts_, p_) do {                                                  \
    const char* ga_ = aA + ((size_t)(ts_) << 18);                            \
    const char* gb_ = aB + ((size_t)(ts_) << 18);                            \
    __builtin_amdgcn_global_load_lds(                                        \
        (const __attribute__((address_space(1))) void*)ga_,                  \
        (__attribute__((address_space(3))) void*)&As[p_][wv << 10], 16,0,0); \
    __builtin_amdgcn_global_load_lds(                                        \
        (const __attribute__((address_space(1))) void*)(ga_ + 1024),         \
        (__attribute__((address_space(3))) void*)&As[p_][(wv<<10)+512],16,0,0);\
    __builtin_amdgcn_global_load_lds(                                        \
        (const __attribute__((address_space(1))) void*)gb_,                  \
        (__attribute__((address_space(3))) void*)&Bs[p_][wv << 9], 16,0,0);  \
} while (0)

__global__ __launch_bounds__(512, 4) void sim_kernel(
    const uint32_t* __restrict__ wsu, float* __restrict__ Y)
{
    __shared__ _Float16 As[2][64 * 128];   // 2 x 16 KB, linear (swz baked)
    __shared__ _Float16 Bs[2][32 * 128];   // 2 x  8 KB

    // XCD-chunked bijective swizzle (2048 % 8 == 0), then tg in high bits:
    // each XCD works one t-group over a contiguous c-range (A-slab reuse).
    const int b    = blockIdx.x;
    const int wgid = (b & 7) * 256 + (b >> 3);
    const int tg   = wgid >> 9;           // 0..3
    const int c    = wgid & 511;          // (n,m) tile id
    const int n0   = (c >> 5) << 6;       // 16 n-tiles of 64
    const int m0   = (c & 31) << 5;       // 32 m-tiles of 32
    const int t0   = tg << 4;

    const int tid  = threadIdx.x;
    const int lane = tid & 63;
    const int wv   = tid >> 6;                  // 0..7
    const int q = lane >> 4, r = lane & 15;
    const int wn = wv >> 1, wm = wv & 1;        // 4x2 wave grid over 64x32

    const char* wsb = (const char*)wsu;
    // contiguous slabs: A = Xh1[(t, n0..n0+63)], B = Xh2[(t, m0..m0+31)]
    const char* aA = wsb + X1H_OFF + ((size_t)(t0 * NN + n0) << 8)
                   + (wv << 11) + (lane << 4);
    const char* aB = wsb + X2H_OFF + ((size_t)(t0 * NN + m0) << 8)
                   + (wv << 10) + (lane << 4);

    f32x4 acc[16];
    #pragma unroll
    for (int i = 0; i < 16; ++i) acc[i] = (f32x4){0.f, 0.f, 0.f, 0.f};

    const int arow = wn * 16 + r;
    const int brow = wm * 16 + r;
    const int ah   = (arow & 7) << 3;     // f16-unit XOR mask
    const int bh   = (brow & 7) << 3;
    const int fcol = q * 8;

    STAGE(0, 0);                           // 3 loads in flight

    #pragma unroll
    for (int ts = 0; ts < 16; ++ts) {
        const int p = ts & 1;
        if (ts < 15) {
            STAGE(ts + 1, p ^ 1);                              // +3 -> 6
            asm volatile("s_waitcnt vmcnt(3)" ::: "memory");   // ts's 3 done
        } else {
            asm volatile("s_waitcnt vmcnt(0)" ::: "memory");
        }
        __builtin_amdgcn_s_barrier();       // all waves' DMA for ts landed
        asm volatile("" ::: "memory");      // no ds_read hoist above barrier

        #pragma unroll
        for (int kc = 0; kc < 4; ++kc) {
            f16x8 af = *(const f16x8*)&As[p][arow * 128 + ((kc*32 + fcol) ^ ah)];
            f16x8 bf = *(const f16x8*)&Bs[p][brow * 128 + ((kc*32 + fcol) ^ bh)];
            acc[ts] = __builtin_amdgcn_mfma_f32_16x16x32_f16(af, bf, acc[ts], 0, 0, 0);
        }

        if (ts < 15) {
            asm volatile("" ::: "memory");
            __builtin_amdgcn_s_barrier();   // reads(ts) done before buf reuse
        }
    }

    // epilogue: col(m)=lane&15, row(n)=(lane>>4)*4+reg (verified mapping)
    const float* n1 = (const float*)(wsb + N1_OFF);
    const float* n2 = (const float*)(wsb + N2_OFF);
    const int m = m0 + wm * 16 + r;
    f32x4 bn4[4];
    {
        const float* p2 = &n2[(size_t)m * TT + t0];
        #pragma unroll
        for (int tq = 0; tq < 4; ++tq) bn4[tq] = ((const f32x4*)p2)[tq];
    }
    const float inv = 1.0f / 128.0f;
    #pragma unroll
    for (int rr = 0; rr < 4; ++rr) {
        const int n = n0 + wn * 16 + q * 4 + rr;
        const float* p1 = &n1[(size_t)n * TT + t0];
        f32x4 an4[4];
        #pragma unroll
        for (int tq = 0; tq < 4; ++tq) an4[tq] = ((const f32x4*)p1)[tq];
        float* yb = Y + ((size_t)n * MM + m) * TT + t0;
        #pragma unroll
        for (int tq = 0; tq < 4; ++tq) {
            f32x4 o;
            #pragma unroll
            for (int e = 0; e < 4; ++e)
                o[e] = (an4[tq][e] + bn4[tq][e] - 2.0f * acc[tq*4 + e][rr]) * inv;
            ((f32x4*)yb)[tq] = o;   // 4 back-to-back 16B -> full 64B line
        }
    }
}

// ---------------- fallback (round-2 verified kernel) --------------------
#define LDA 132
#define LDN 17

__global__ __launch_bounds__(512, 4) void sim_kernel_fb(
    const float* __restrict__ X1, const float* __restrict__ X2,
    float* __restrict__ Y)
{
    __shared__ _Float16 As[2][64 * LDA];
    __shared__ _Float16 Bs[2][32 * LDA];
    __shared__ float an[64 * LDN];
    __shared__ float bn[32 * LDN];

    const int b   = blockIdx.x;
    const int clo = b & 7;
    const int tg  = (b >> 3) & 3;
    const int chi = b >> 5;
    const int c   = (chi << 3) | clo;
    const int n0  = (c >> 5) << 6;
    const int m0  = (c & 31) << 5;
    const int t0  = tg << 4;

    const int tid  = threadIdx.x;
    const int lane = tid & 63;
    const int wave = tid >> 6;
    const int q = lane >> 4, r = lane & 15;
    const int wn = wave >> 1, wm = wave & 1;

    const int arow = tid >> 3;
    const int acol = (tid & 7) << 4;
    const int brow = tid >> 4;
    const int bcol = (tid & 15) << 3;

    const float* pA = X1 + ((size_t)(n0 + arow) * TT + t0) * DD + acol;
    const float* pB = X2 + ((size_t)(m0 + brow) * TT + t0) * DD + bcol;

    f32x4 acc[16];
    #pragma unroll
    for (int i = 0; i < 16; ++i) acc[i] = (f32x4){0.f, 0.f, 0.f, 0.f};

    f32x4 uA[4];
    f32x4 uB[2];
    uA[0] = ((const f32x4*)pA)[0]; uA[1] = ((const f32x4*)pA)[1];
    uA[2] = ((const f32x4*)pA)[2]; uA[3] = ((const f32x4*)pA)[3];
    uB[0] = ((const f32x4*)pB)[0]; uB[1] = ((const f32x4*)pB)[1];

    #pragma unroll
    for (int tl = 0; tl < 16; ++tl) {
        _Float16* __restrict__ Abuf = As[tl & 1];
        _Float16* __restrict__ Bbuf = Bs[tl & 1];

        float sA = 0.f;
        #pragma unroll
        for (int j = 0; j < 4; ++j)
            sA += uA[j][0]*uA[j][0] + uA[j][1]*uA[j][1]
                + uA[j][2]*uA[j][2] + uA[j][3]*uA[j][3];
        f16x8 hA0, hA1;
        #pragma unroll
        for (int e = 0; e < 4; ++e) { hA0[e] = (_Float16)uA[0][e]; hA0[e+4] = (_Float16)uA[1][e]; }
        #pragma unroll
        for (int e = 0; e < 4; ++e) { hA1[e] = (_Float16)uA[2][e]; hA1[e+4] = (_Float16)uA[3][e]; }
        sA += __shfl_xor(sA, 1); sA += __shfl_xor(sA, 2); sA += __shfl_xor(sA, 4);

        float sB = uB[0][0]*uB[0][0] + uB[0][1]*uB[0][1]
                 + uB[0][2]*uB[0][2] + uB[0][3]*uB[0][3]
                 + uB[1][0]*uB[1][0] + uB[1][1]*uB[1][1]
                 + uB[1][2]*uB[1][2] + uB[1][3]*uB[1][3];
        f16x8 hB;
        #pragma unroll
        for (int e = 0; e < 4; ++e) { hB[e] = (_Float16)uB[0][e]; hB[e+4] = (_Float16)uB[1][e]; }
        sB += __shfl_xor(sB, 1); sB += __shfl_xor(sB, 2);
        sB += __shfl_xor(sB, 4); sB += __shfl_xor(sB, 8);

        *(f16x8*)&Abuf[arow * LDA + acol]     = hA0;
        *(f16x8*)&Abuf[arow * LDA + acol + 8] = hA1;
        *(f16x8*)&Bbuf[brow * LDA + bcol]     = hB;
        if ((tid & 7)  == 0) an[arow * LDN + tl] = sA;
        if ((tid & 15) == 0) bn[brow * LDN + tl] = sB;

        __syncthreads();

        if (tl < 15) {
            const float* nA = pA + (size_t)(tl + 1) * DD;
            const float* nB = pB + (size_t)(tl + 1) * DD;
            uA[0] = ((const f32x4*)nA)[0]; uA[1] = ((const f32x4*)nA)[1];
            uA[2] = ((const f32x4*)nA)[2]; uA[3] = ((const f32x4*)nA)[3];
            uB[0] = ((const f32x4*)nB)[0]; uB[1] = ((const f32x4*)nB)[1];
        }

        #pragma unroll
        for (int kc = 0; kc < 4; ++kc) {
            f16x8 af = *(const f16x8*)&Abuf[(wn*16 + r) * LDA + kc*32 + q*8];
            f16x8 bf = *(const f16x8*)&Bbuf[(wm*16 + r) * LDA + kc*32 + q*8];
            acc[tl] = __builtin_amdgcn_mfma_f32_16x16x32_f16(af, bf, acc[tl], 0, 0, 0);
        }
    }

    float bnv[16];
    {
        const float* pb = &bn[(wm*16 + r) * LDN];
        #pragma unroll
        for (int e = 0; e < 16; ++e) bnv[e] = pb[e];
    }
    const float inv = 1.0f / 128.0f;
    #pragma unroll
    for (int rr = 0; rr < 4; ++rr) {
        const float* pa = &an[(wn*16 + q*4 + rr) * LDN];
        float anv[16];
        #pragma unroll
        for (int e = 0; e < 16; ++e) anv[e] = pa[e];
        const size_t n = (size_t)(n0 + wn*16 + q*4 + rr);
        const size_t m = (size_t)(m0 + wm*16 + r);
        float* yb = Y + (n * MM + m) * TT + t0;
        #pragma unroll
        for (int tq = 0; tq < 4; ++tq) {
            f32x4 o;
            #pragma unroll
            for (int e = 0; e < 4; ++e) {
                const int tl = tq*4 + e;
                o[e] = (anv[tl] + bnv[tl] - 2.0f * acc[tl][rr]) * inv;
            }
            ((f32x4*)yb)[tq] = o;
        }
    }
}

extern "C" void kernel_launch(void* const* d_in, const int* in_sizes, int n_in,
                              void* d_out, int out_size, void* d_ws, size_t ws_size,
                              hipStream_t stream) {
    const float* X1 = (const float*)d_in[0];
    const float* X2 = (const float*)d_in[1];
    float* Y = (float*)d_out;
    if (d_ws != nullptr && ws_size >= WS_NEED) {
        prep_kernel<<<dim3(32768), dim3(256), 0, stream>>>(X1, X2, (uint32_t*)d_ws);
        sim_kernel<<<dim3(2048), dim3(512), 0, stream>>>((const uint32_t*)d_ws, Y);
    } else {
        sim_kernel_fb<<<dim3(2048), dim3(512), 0, stream>>>(X1, X2, Y);
    }
}